// Round 5
// baseline (80.916 us; speedup 1.0000x reference)
//
#include <hip/hip_runtime.h>
#include <math.h>

// CapsuleLinear routing, fp32 — priors eliminated; DPP reduces, SGPR broadcast.
// logits_n = x_n . (W^T out_hat);  out = W . (sum_n p_n x_n)
// B=64, N=1152, I=8, O=64, L=16, 3 iters.
// Grid: 4096 blocks = one per (b,o). T=128 (2 waves), 9 rows/thread.
// Reductions: in-wave DPP adds (VALU pipe, row_shr direction!), one barrier
// per iteration for the 2-wave combine, epilogue redundant per lane with
// readlane->SGPR broadcast.

#define NCAPS 1152
#define ILEN  8
#define OCAPS 64
#define OLEN  16
#define T     128
#define NW    2
#define RPT   9        // 1152 / 128
#define NITER 3

template<int CTRL>
__device__ __forceinline__ float dpp_mov0(float x) {
    int xi = __builtin_bit_cast(int, x);
    int r  = __builtin_amdgcn_update_dpp(0, xi, CTRL, 0xf, 0xf, true);
    return __builtin_bit_cast(float, r);
}

// Full wave64 sum; result valid in lane 63. 6 dependent VALU ops.
// row_shr:N (0x11N) = lane i reads lane i-N  (accumulate toward lane 15 of row).
__device__ __forceinline__ float wave_sum63(float v) {
    v += dpp_mov0<0x111>(v);   // row_shr:1
    v += dpp_mov0<0x112>(v);   // row_shr:2
    v += dpp_mov0<0x114>(v);   // row_shr:4
    v += dpp_mov0<0x118>(v);   // row_shr:8  -> lane 15+16r = row r sum
    v += dpp_mov0<0x142>(v);   // row_bcast:15 -> lane 63 = row3+row2, lane 31 = row1+row0
    v += dpp_mov0<0x143>(v);   // row_bcast:31 -> lane 63 = total
    return v;
}

// Sum over each 16-lane row; result valid in lane 15 of each row.
__device__ __forceinline__ float row16_sum(float v) {
    v += dpp_mov0<0x111>(v);
    v += dpp_mov0<0x112>(v);
    v += dpp_mov0<0x114>(v);
    v += dpp_mov0<0x118>(v);
    return v;
}

__device__ __forceinline__ float bcast_lane(float v, int lane) {
    return __builtin_bit_cast(float,
        __builtin_amdgcn_readlane(__builtin_bit_cast(int, v), lane));
}

__global__ __launch_bounds__(T, 4) void caps_kernel(const float* __restrict__ x,
                                                    const float* __restrict__ w,
                                                    float* __restrict__ dout,
                                                    int probs_base) {
    const int tid  = threadIdx.x;
    const int lane = tid & 63;
    const int wid  = tid >> 6;
    const int l16  = lane & 15;
    const int o = blockIdx.x & (OCAPS - 1);
    const int b = blockIdx.x >> 6;

    // per-iteration slots, 16B-aligned: [0..3]=s0..3, [4..7]=s4..7, [8]=z
    __shared__ __align__(16) float red[NITER + 1][NW][12];

    // W row for this lane (replicated across the 4 row-groups of the wave)
    float wreg[ILEN];
    {
        const float4* wp = (const float4*)(w + ((size_t)o * OLEN + l16) * ILEN);
        float4 a = wp[0], c = wp[1];
        wreg[0] = a.x; wreg[1] = a.y; wreg[2] = a.z; wreg[3] = a.w;
        wreg[4] = c.x; wreg[5] = c.y; wreg[6] = c.z; wreg[7] = c.w;
    }

    // x rows -> registers (coalesced float4 pairs)
    const float* xb = x + (size_t)b * (NCAPS * ILEN);
    float xr[RPT][ILEN];
    #pragma unroll
    for (int k = 0; k < RPT; ++k) {
        const float4* q = (const float4*)(xb + (size_t)(tid + k * T) * ILEN);
        float4 a = q[0], c = q[1];
        xr[k][0] = a.x; xr[k][1] = a.y; xr[k][2] = a.z; xr[k][3] = a.w;
        xr[k][4] = c.x; xr[k][5] = c.y; xr[k][6] = c.z; xr[k][7] = c.w;
    }

    float e[RPT];
    float ysg[ILEN];   // uniform (readlane) -> SGPRs

    #pragma unroll
    for (int it = 0; it <= NITER; ++it) {
        float s[ILEN];
        float z = 0.0f;
        if (it == 0) {
            #pragma unroll
            for (int i = 0; i < ILEN; ++i) {
                float acc = xr[0][i];
                #pragma unroll
                for (int k = 1; k < RPT; ++k) acc += xr[k][i];
                s[i] = acc;
            }
        } else {
            #pragma unroll
            for (int k = 0; k < RPT; ++k) {
                float lg = xr[k][0] * ysg[0];
                #pragma unroll
                for (int i = 1; i < ILEN; ++i) lg = fmaf(xr[k][i], ysg[i], lg);
                e[k] = __expf(lg);   // |lg| small; max-subtraction unneeded
            }
            #pragma unroll
            for (int i = 0; i < ILEN; ++i) {
                float acc = e[0] * xr[0][i];
                #pragma unroll
                for (int k = 1; k < RPT; ++k) acc = fmaf(e[k], xr[k][i], acc);
                s[i] = acc;
            }
            z = e[0];
            #pragma unroll
            for (int k = 1; k < RPT; ++k) z += e[k];
        }

        // in-wave DPP reduce (VALU pipe); totals land in lane 63
        #pragma unroll
        for (int i = 0; i < ILEN; ++i) s[i] = wave_sum63(s[i]);
        if (it > 0) z = wave_sum63(z);

        if (lane == 63) {
            *(float4*)&red[it][wid][0] = make_float4(s[0], s[1], s[2], s[3]);
            *(float4*)&red[it][wid][4] = make_float4(s[4], s[5], s[6], s[7]);
            red[it][wid][8] = z;
        }
        __syncthreads();   // one barrier per iteration (slots indexed by it)

        float4 a0 = *(const float4*)&red[it][0][0];
        float4 a1 = *(const float4*)&red[it][0][4];
        float4 b0 = *(const float4*)&red[it][1][0];
        float4 b1 = *(const float4*)&red[it][1][4];
        float sc[ILEN];
        sc[0] = a0.x + b0.x; sc[1] = a0.y + b0.y; sc[2] = a0.z + b0.z; sc[3] = a0.w + b0.w;
        sc[4] = a1.x + b1.x; sc[5] = a1.y + b1.y; sc[6] = a1.z + b1.z; sc[7] = a1.w + b1.w;
        const float zc   = (it == 0) ? (float)NCAPS : (red[it][0][8] + red[it][1][8]);
        const float zinv = 1.0f / zc;

        // out_l for this lane's l16 (redundant across row-groups and waves)
        float ol = wreg[0] * sc[0];
        #pragma unroll
        for (int i = 1; i < ILEN; ++i) ol = fmaf(wreg[i], sc[i], ol);
        ol *= zinv;

        if (it < NITER) {
            float n2 = row16_sum(ol * ol);
            n2 = bcast_lane(n2, 15);
            const float inv = 1.0f / fmaxf(sqrtf(n2), 1e-12f);
            const float oh = ol * inv;
            #pragma unroll
            for (int i = 0; i < ILEN; ++i) {
                float t = row16_sum(wreg[i] * oh);
                ysg[i] = bcast_lane(t, 15);
            }
        } else {
            if (tid < OLEN) dout[(size_t)blockIdx.x * OLEN + tid] = ol;
            float* pp = dout + (size_t)probs_base + (size_t)blockIdx.x * NCAPS;
            #pragma unroll
            for (int k = 0; k < RPT; ++k) pp[tid + k * T] = e[k] * zinv;
        }
    }
}

extern "C" void kernel_launch(void* const* d_in, const int* in_sizes, int n_in,
                              void* d_out, int out_size, void* d_ws, size_t ws_size,
                              hipStream_t stream) {
    const float* x = (const float*)d_in[0];
    const float* w = (const float*)d_in[1];
    float* out = (float*)d_out;
    const int Bv = in_sizes[0] / (NCAPS * ILEN);   // 64
    const int nblocks = Bv * OCAPS;                // 4096
    const int probs_base = nblocks * OLEN;         // 65536
    caps_kernel<<<dim3(nblocks), dim3(T), 0, stream>>>(x, w, out, probs_base);
}

// Round 6
// 72.631 us; speedup vs baseline: 1.1141x; 1.1141x over previous
//
#include <hip/hip_runtime.h>
#include <math.h>

// CapsuleLinear routing — MFMA formulation.
// logits = Xb @ Y (K=8 pad 32), S_aug = P^T @ [Xb | 1] (K=n, 16 per MFMA slot-pair)
// using only __builtin_amdgcn_mfma_f32_16x16x32_bf16 (verified layouts:
// A[m=lane&15][k=quad*8+j], C/D[col=lane&15][row=quad*4+reg]).
// Block = (b, og): 64 x 4 = 256 blocks, T=512 (8 waves), 9 n-tiles/wave.

#define NCAPS 1152
#define ILEN  8
#define OCAPS 64
#define OLEN  16
#define T     512
#define NWAVE 8
#define TPW   9          // n-tiles of 16 per wave (72 total)
#define NITER 3
#define OG    16
#define XT_PITCH 1156    // ushorts per xaugT row (2312 B: 8B-aligned, 577*... -> bank-clean)

typedef __attribute__((ext_vector_type(8))) short short8;
typedef __attribute__((ext_vector_type(4))) float f32x4;

__device__ __forceinline__ unsigned f2bf_u(float f) {   // RNE float->bf16 bits
    unsigned u = __builtin_bit_cast(unsigned, f);
    return (u + 0x7FFFu + ((u >> 16) & 1u)) >> 16;
}
__device__ __forceinline__ unsigned pack2(float a, float b) {
    return f2bf_u(a) | (f2bf_u(b) << 16);
}
__device__ __forceinline__ float bf2f(unsigned h) {
    return __builtin_bit_cast(float, h << 16);
}
__device__ __forceinline__ short8 s8_from(unsigned a, unsigned b, unsigned c, unsigned d) {
    uint4 t = make_uint4(a, b, c, d);
    return __builtin_bit_cast(short8, t);
}

template<int CTRL>
__device__ __forceinline__ float dpp_mov0(float x) {
    int xi = __builtin_bit_cast(int, x);
    int r  = __builtin_amdgcn_update_dpp(0, xi, CTRL, 0xf, 0xf, true);
    return __builtin_bit_cast(float, r);
}
// Sum over each 16-lane row; valid in lane 15 of each row (row_shr dir — verified R5).
__device__ __forceinline__ float row16_sum(float v) {
    v += dpp_mov0<0x111>(v);
    v += dpp_mov0<0x112>(v);
    v += dpp_mov0<0x114>(v);
    v += dpp_mov0<0x118>(v);
    return v;
}

__global__ __launch_bounds__(T, 2) void caps_kernel(const float* __restrict__ x,
                                                    const float* __restrict__ w,
                                                    float* __restrict__ dout,
                                                    int probs_base) {
    const int tid  = threadIdx.x;
    const int lane = tid & 63;
    const int wid  = tid >> 6;
    const int l16  = lane & 15;
    const int quad = lane >> 4;
    const bool q0  = (quad == 0);
    const int b  = blockIdx.x >> 2;
    const int og = blockIdx.x & 3;

    __shared__ __align__(16) unsigned short xA[NCAPS][ILEN];       // 18432 B, bf16 rows
    __shared__ __align__(16) unsigned short xaugT[10 * XT_PITCH];  // 23120 B, rows j=0..7 x^T, 8=ones, 9=zeros
    __shared__ __align__(16) unsigned short Yl[OLEN][16];          // 512 B, Y[o][k] bf16
    __shared__ __align__(16) float Wl[OLEN][OLEN][ILEN];           // 8192 B, W[o][l][i]
    __shared__ float Scmb[NWAVE][OLEN][17];                        // 8704 B
    __shared__ float ZL[OLEN];

    // ---- prologue: stage W and x (two layouts, bf16) ----
    ((float4*)&Wl[0][0][0])[tid] = ((const float4*)(w + (size_t)og * OG * OLEN * ILEN))[tid];

    const float4* xs = (const float4*)(x + (size_t)b * NCAPS * ILEN);
    #pragma unroll
    for (int p = 0; p < 3; ++p) {
        const int row = p * T + tid;
        if (row < NCAPS) {
            float4 x0 = xs[row * 2], x1 = xs[row * 2 + 1];
            unsigned h0 = f2bf_u(x0.x), h1 = f2bf_u(x0.y), h2 = f2bf_u(x0.z), h3 = f2bf_u(x0.w);
            unsigned h4 = f2bf_u(x1.x), h5 = f2bf_u(x1.y), h6 = f2bf_u(x1.z), h7 = f2bf_u(x1.w);
            *(uint4*)&xA[row][0] = make_uint4(h0 | (h1 << 16), h2 | (h3 << 16),
                                              h4 | (h5 << 16), h6 | (h7 << 16));
            xaugT[0 * XT_PITCH + row] = (unsigned short)h0;
            xaugT[1 * XT_PITCH + row] = (unsigned short)h1;
            xaugT[2 * XT_PITCH + row] = (unsigned short)h2;
            xaugT[3 * XT_PITCH + row] = (unsigned short)h3;
            xaugT[4 * XT_PITCH + row] = (unsigned short)h4;
            xaugT[5 * XT_PITCH + row] = (unsigned short)h5;
            xaugT[6 * XT_PITCH + row] = (unsigned short)h6;
            xaugT[7 * XT_PITCH + row] = (unsigned short)h7;
            xaugT[8 * XT_PITCH + row] = 0x3F80;   // ones column (z)
        }
    }
    for (int idx = tid; idx < XT_PITCH; idx += T) xaugT[9 * XT_PITCH + idx] = 0;  // zero row (j>=9 clamp)
    __syncthreads();

    // per-lane bases (tile offsets are compile-time immediates)
    const int jr = (l16 < 9) ? l16 : 9;                         // S-GEMM B row (clamped to zero row)
    const unsigned short* xTw = xaugT + jr * XT_PITCH + wid * (TPW * 16) + 4 * quad;
    const unsigned short* xAw = &xA[wid * (TPW * 16) + l16][0];

    const short8 zs = {0, 0, 0, 0, 0, 0, 0, 0};
    const f32x4  zc = {0.f, 0.f, 0.f, 0.f};

    unsigned st0[TPW], st1[TPW];   // it=3 packed e (bf16x2)

    #pragma unroll
    for (int it = 0; it <= NITER; ++it) {
        short8 bL = zs;
        if (it > 0 && q0) bL = *(const short8*)&Yl[l16][0];     // Y[o][k0..7]

        f32x4 sacc = zc;
        #pragma unroll
        for (int tt = 0; tt < TPW; ++tt) {
            // S-GEMM B: xaug rows n0+4*quad+{0..3} at column j=l16 (j>=4 slots zero)
            uint2 t2 = *(const uint2*)(xTw + tt * 16);
            short8 bs = s8_from(t2.x, t2.y, 0u, 0u);

            short8 as;
            if (it == 0) {
                as = s8_from(0x3F803F80u, 0x3F803F80u, 0u, 0u);   // P = 1
            } else {
                short8 aL = q0 ? *(const short8*)(xAw + tt * 128) : zs;  // x row, k0..7
                f32x4 d = __builtin_amdgcn_mfma_f32_16x16x32_bf16(aL, bL, zc, 0, 0, 0);
                float e0 = __expf(d[0]), e1 = __expf(d[1]);
                float e2 = __expf(d[2]), e3 = __expf(d[3]);
                unsigned p0 = pack2(e0, e1), p1 = pack2(e2, e3);
                if (it == NITER) { st0[tt] = p0; st1[tt] = p1; }
                as = s8_from(p0, p1, 0u, 0u);
            }
            sacc = __builtin_amdgcn_mfma_f32_16x16x32_bf16(as, bs, sacc, 0, 0, 0);
        }

        // write partial S_aug: D rows o = 4*quad+r, cols j = l16
        #pragma unroll
        for (int r = 0; r < 4; ++r) Scmb[wid][4 * quad + r][l16] = sacc[r];
        __syncthreads();

        if (tid < 256) {
            const int o = tid >> 4, l = tid & 15;
            float sv[9];
            #pragma unroll
            for (int i = 0; i < 9; ++i) {
                float t = Scmb[0][o][i];
                #pragma unroll
                for (int ww = 1; ww < NWAVE; ++ww) t += Scmb[ww][o][i];
                sv[i] = t;
            }
            const float zinv = 1.0f / sv[8];
            const float* wrow = &Wl[o][l][0];
            float outl = wrow[0] * sv[0];
            #pragma unroll
            for (int i = 1; i < ILEN; ++i) outl = fmaf(wrow[i], sv[i], outl);
            outl *= zinv;

            if (it < NITER) {
                float n2 = outl * outl;
                n2 += __shfl_xor(n2, 1);
                n2 += __shfl_xor(n2, 2);
                n2 += __shfl_xor(n2, 4);
                n2 += __shfl_xor(n2, 8);
                const float inv = 1.0f / fmaxf(sqrtf(n2), 1e-12f);
                const float oh = outl * inv;
                #pragma unroll
                for (int i = 0; i < ILEN; ++i) {
                    float t = row16_sum(wrow[i] * oh);
                    if (l == 15) Yl[o][i] = (unsigned short)f2bf_u(t);
                }
            } else {
                dout[(((size_t)(b * OCAPS + og * OG + o)) << 4) + l] = outl;
                if (l == 0) ZL[o] = zinv;
            }
        }
        __syncthreads();
    }

    // ---- probs: unpack stashed e (bf16) * zinv, store ----
    {
        const float zi = ZL[l16];
        float* pb = dout + (size_t)probs_base
                  + (size_t)(b * OCAPS + og * OG + l16) * NCAPS
                  + wid * (TPW * 16) + 4 * quad;
        #pragma unroll
        for (int tt = 0; tt < TPW; ++tt) {
            unsigned p0 = st0[tt], p1 = st1[tt];
            pb[tt * 16 + 0] = bf2f(p0 & 0xFFFFu) * zi;
            pb[tt * 16 + 1] = bf2f(p0 >> 16) * zi;
            pb[tt * 16 + 2] = bf2f(p1 & 0xFFFFu) * zi;
            pb[tt * 16 + 3] = bf2f(p1 >> 16) * zi;
        }
    }
}

extern "C" void kernel_launch(void* const* d_in, const int* in_sizes, int n_in,
                              void* d_out, int out_size, void* d_ws, size_t ws_size,
                              hipStream_t stream) {
    const float* x = (const float*)d_in[0];
    const float* w = (const float*)d_in[1];
    float* out = (float*)d_out;
    const int Bv = in_sizes[0] / (NCAPS * ILEN);        // 64
    const int nblocks = Bv * (OCAPS / OG);              // 256
    const int probs_base = Bv * OCAPS * OLEN;           // 65536
    caps_kernel<<<dim3(nblocks), dim3(T), 0, stream>>>(x, w, out, probs_base);
}